// Round 11
// baseline (54.267 us; speedup 1.0000x reference)
//
#include <hip/hip_runtime.h>
#include <hip/hip_bf16.h>
#include <stdint.h>

#define ENT 250000
#define RELSZ 64
#define D 128
#define BATCH 32768
#define KNEG 8

// ---------------- workspace layout (byte offsets) ----------------
// t1       :       0 .. 32768    (64x128 f32)  out_rel - (n_inmap.out_rel) n_inmap
// t2       :   32768 .. 65536    (64x128 f32)  in_rel  - (n_outmap.in_rel) n_outmap
// RR       :   65536 .. 81920    (64x64  f32)  in_rel[i] . out_rel[p]
// C        :   81920 .. 100352   (4608 int)    block bucket counts -> exclusive scan
// rank_pos :  100352 .. 165888   (32768 u16)   block-local stable rank
// rank_neg :  165888 .. 690176   (262144 u16)
// buf_pos  :  690176 .. 821248   (32768 f32)   raw dots, pair order
// buf_neg  :  821248 .. 1869824  (262144 f32)
// LESSONS: R4: no __threadfence last-block pattern (~73us). R7: no single-block
// grid-serial scans (~10GB/s). R8: no hipMemsetAsync on scratch (~72us fill).
// R9/R10: no per-block staging+barrier prologue in the gather kernel; per-pair
// independent dest loads consumed at the end hide perfectly (R6 structure).

__device__ __forceinline__ float logsig(float x) {
  return fminf(x, 0.f) - log1pf(expf(-fabsf(x)));
}

// K1 fused: blocks [0,4608) main dots -> buf (pair order, no dest needed);
// [4608,5760) counting + stable block-local ranks; [5760,5792) tables;
// [5792,5824) zero d_out. All four classes are mutually independent.
__global__ void __launch_bounds__(256, 4)
k_fused(const float* __restrict__ in_ent, const float* __restrict__ out_ent,
        const float* __restrict__ in_rel, const float* __restrict__ out_rel,
        const float* __restrict__ in_map, const float* __restrict__ out_map,
        const int* __restrict__ in_lab, const int* __restrict__ pos_lab,
        const int* __restrict__ neg_lab,
        float* t1, float* t2, float* __restrict__ RR,
        int* __restrict__ C, uint16_t* __restrict__ rank_pos,
        uint16_t* __restrict__ rank_neg,
        float* __restrict__ buf_pos, float* __restrict__ buf_neg,
        float* __restrict__ out) {
  __shared__ float ls[4];
  __shared__ float sri[2][128];
  __shared__ int wc[4][4];
  int blk = blockIdx.x, t = threadIdx.x;

  if (blk < 4608) {
    // ---- main: 4 lanes per pair, 16 pairs per wave, dots only ----
    int wave = t >> 6, lane = t & 63;
    int q = lane & 3, g = lane >> 2;
    bool is_pos = blk < 512;
    int w = (is_pos ? blk : blk - 512) * 4 + wave;
    int i = w * 16 + g;
    int il = is_pos ? in_lab[i] : in_lab[i >> 3];
    int o  = is_pos ? pos_lab[i] : neg_lab[i];
    bool ei = il < ENT; int iid = ei ? il : il - ENT;
    bool eo = o < ENT;  int oid = eo ? o : o - ENT;
    // key!=0 rows read t1/t2 mid-write -> garbage dot, recomputed in K3.
    const float* Lp = (ei ? in_ent + (size_t)iid * D : t2 + (size_t)iid * D) + q * 4;
    const float* Rp = (eo ? out_ent + (size_t)oid * D : t1 + (size_t)oid * D) + q * 4;
    float4 L[8], R[8];
#pragma unroll
    for (int k = 0; k < 8; k++) L[k] = *(const float4*)(Lp + k * 16);
#pragma unroll
    for (int k = 0; k < 8; k++) R[k] = *(const float4*)(Rp + k * 16);
    float p = 0.f;
#pragma unroll
    for (int k = 0; k < 8; k++)
      p += L[k].x * R[k].x + L[k].y * R[k].y + L[k].z * R[k].z + L[k].w * R[k].w;
    p += __shfl_xor(p, 1, 64);
    p += __shfl_xor(p, 2, 64);
    if (q == 0) {
      if (is_pos) buf_pos[i] = p;
      else        buf_neg[i] = p;
    }
    return;
  }

  if (blk < 5760) {
    // ---- counting + stable block-local ranks (R6-proven) ----
    int bb = blk - 4608;
    int wave = t >> 6, lane = t & 63;
    bool is_pos = bb < 128;
    int key, i;
    if (is_pos) {
      i = bb * 256 + t;
      int il = in_lab[i], pl = pos_lab[i];
      key = ((il >= ENT) ? 2 : 0) | ((pl >= ENT) ? 1 : 0);
    } else {
      i = (bb - 128) * 256 + t;
      int il = in_lab[i >> 3], nl = neg_lab[i];
      key = ((il >= ENT) ? 2 : 0) | ((nl >= ENT) ? 1 : 0);
    }
    unsigned long long m[4];
#pragma unroll
    for (int v = 0; v < 4; v++) m[v] = __ballot(key == v);
    if (lane < 4) wc[wave][lane] = __popcll(m[lane]);
    int wrank = __popcll(m[key] & ((1ull << lane) - 1ull));
    __syncthreads();
    if (t < 4) {
      int s = wc[0][t] + wc[1][t] + wc[2][t] + wc[3][t];
      int idx = is_pos ? (t * 128 + bb) : (512 + t * 1024 + (bb - 128));
      C[idx] = s;
    }
    int wpre = 0;
    for (int w2 = 0; w2 < wave; w2++) wpre += wc[w2][key];
    uint16_t rk = (uint16_t)(wpre + wrank);
    if (is_pos) rank_pos[i] = rk;
    else        rank_neg[i] = rk;
    return;
  }

  if (blk < 5792) {
    // ---- tables: 2 rel rows per block ----
    int sub = t >> 7, tt = t & 127;
    int p = (blk - 5760) * 2 + sub;
    float im = in_map[p * D + tt], om = out_map[p * D + tt];
    float ro = out_rel[p * D + tt], ri = in_rel[p * D + tt];
    float v, r, n_im, n_om;
    v = im * im;
#pragma unroll
    for (int off = 32; off > 0; off >>= 1) v += __shfl_xor(v, off, 64);
    if ((t & 63) == 0) ls[t >> 6] = v;
    __syncthreads();
    r = ls[sub * 2] + ls[sub * 2 + 1];
    n_im = im / fmaxf(sqrtf(r), 1e-12f);
    __syncthreads();
    v = om * om;
#pragma unroll
    for (int off = 32; off > 0; off >>= 1) v += __shfl_xor(v, off, 64);
    if ((t & 63) == 0) ls[t >> 6] = v;
    __syncthreads();
    r = ls[sub * 2] + ls[sub * 2 + 1];
    n_om = om / fmaxf(sqrtf(r), 1e-12f);
    __syncthreads();
    v = n_im * ro;
#pragma unroll
    for (int off = 32; off > 0; off >>= 1) v += __shfl_xor(v, off, 64);
    if ((t & 63) == 0) ls[t >> 6] = v;
    __syncthreads();
    float d1 = ls[sub * 2] + ls[sub * 2 + 1];
    __syncthreads();
    v = n_om * ri;
#pragma unroll
    for (int off = 32; off > 0; off >>= 1) v += __shfl_xor(v, off, 64);
    if ((t & 63) == 0) ls[t >> 6] = v;
    __syncthreads();
    float d2 = ls[sub * 2] + ls[sub * 2 + 1];
    t1[p * D + tt] = ro - d1 * n_im;
    t2[p * D + tt] = ri - d2 * n_om;
    sri[sub][tt] = ri;
    __syncthreads();
    int half = t >> 7, lq = t & 127;
    if (lq < RELSZ) {
      int pr = (blk - 5760) * 2 + half;
      const float* rq = out_rel + lq * D;
      const float* s = sri[half];
      float acc = 0.f;
#pragma unroll 8
      for (int d = 0; d < D; d += 4) {
        float4 r4 = *(const float4*)(rq + d);
        acc += s[d] * r4.x + s[d + 1] * r4.y + s[d + 2] * r4.z + s[d + 3] * r4.w;
      }
      RR[pr * RELSZ + lq] = acc;
    }
    return;
  }

  // ---- zero d_out ----
  int idx = (blk - 5792) * 256 + t;
  ((float4*)out)[idx] = make_float4(0.f, 0.f, 0.f, 0.f);
}

// K2: in-place exclusive scan of C[0..4607]. 1 block x 256 threads, 18 elems each.
__global__ void k_scan(int* __restrict__ C) {
  int t = threadIdx.x, lane = t & 63, w = t >> 6;
  int base = t * 18;
  int v[18];
  int s = 0;
#pragma unroll
  for (int j = 0; j < 18; j++) { v[j] = C[base + j]; s += v[j]; }
  int inc = s;
#pragma unroll
  for (int off = 1; off < 64; off <<= 1) {
    int x = __shfl_up(inc, off, 64);
    if (lane >= off) inc += x;
  }
  __shared__ int wsum[4];
  if (lane == 63) wsum[w] = inc;
  __syncthreads();
  int wpre = 0;
  for (int i = 0; i < w; i++) wpre += wsum[i];
  int run = wpre + inc - s;
#pragma unroll
  for (int j = 0; j < 18; j++) { C[base + j] = run; run += v[j]; }
}

// K3: permute + combine. Blocks [0,128) pos (1 pair/thread), [128,1152) neg.
// Rare key!=0 pairs recompute their dot from the now-valid tables.
__global__ void k_final(const float* __restrict__ in_ent, const float* __restrict__ out_ent,
                        const float* __restrict__ t1, const float* __restrict__ t2,
                        const float* __restrict__ RR,
                        const int* __restrict__ in_lab, const int* __restrict__ pos_lab,
                        const int* __restrict__ neg_lab,
                        const int* __restrict__ C, const uint16_t* __restrict__ rank_pos,
                        const uint16_t* __restrict__ rank_neg,
                        const float* __restrict__ buf_pos, const float* __restrict__ buf_neg,
                        float* __restrict__ out) {
  int blk = blockIdx.x, t = threadIdx.x;
  bool is_pos = blk < 128;
  int i = (is_pos ? blk : blk - 128) * 256 + t;

  int il = is_pos ? in_lab[i] : in_lab[i >> 3];
  int o  = is_pos ? pos_lab[i] : neg_lab[i];
  bool ei = il < ENT, eo = o < ENT;
  int key = (ei ? 0 : 2) | (eo ? 0 : 1);
  int rk = is_pos ? (int)rank_pos[i] : (int)rank_neg[i];
  int cidx = is_pos ? (key * 128 + (i >> 8)) : (512 + key * 1024 + (i >> 8));
  int cbase = C[cidx];
  float dot = is_pos ? buf_pos[i] : buf_neg[i];

  if (key) {  // rare (~150 of 294912): recompute from valid tables
    int iid = ei ? il : il - ENT, oid = eo ? o : o - ENT;
    if (key == 3) {
      dot = RR[iid * RELSZ + oid];
    } else {
      const float* Lp = ei ? in_ent + (size_t)iid * D : t2 + (size_t)iid * D;
      const float* Rp = eo ? out_ent + (size_t)oid * D : t1 + (size_t)oid * D;
      float s = 0.f;
#pragma unroll 8
      for (int d = 0; d < D; d += 4) {
        float4 a = *(const float4*)(Lp + d);
        float4 b = *(const float4*)(Rp + d);
        s += a.x * b.x + a.y * b.y + a.z * b.z + a.w * b.w;
      }
      dot = s;
    }
  }

  if (is_pos) {
    int dest = cbase + rk;
    atomicAdd(out + dest, -logsig(dot));
  } else {
    int dest = (cbase + rk - BATCH) >> 3;
    float val = -logsig(-dot);
    // 8-lane tree combine (one row's 8 negs are consecutive threads)
    float v = val;
    int d = dest, eq = 1;
#pragma unroll
    for (int off = 1; off <= 4; off <<= 1) {
      float vv = __shfl_xor(v, off, 64);
      int dd = __shfl_xor(d, off, 64);
      int ee = __shfl_xor(eq, off, 64);
      eq = eq & ee & (dd == d ? 1 : 0);
      v += vv;
    }
    if (eq) {
      if ((t & 7) == 0) atomicAdd(out + d, v);
    } else {
      atomicAdd(out + dest, val);
    }
  }
}

extern "C" void kernel_launch(void* const* d_in, const int* in_sizes, int n_in,
                              void* d_out, int out_size, void* d_ws, size_t ws_size,
                              hipStream_t stream) {
  const float* in_ent  = (const float*)d_in[0];
  const float* out_ent = (const float*)d_in[1];
  const float* in_rel  = (const float*)d_in[2];
  const float* out_rel = (const float*)d_in[3];
  const float* in_map  = (const float*)d_in[4];
  const float* out_map = (const float*)d_in[5];
  const int* in_lab  = (const int*)d_in[6];
  const int* pos_lab = (const int*)d_in[7];
  const int* neg_lab = (const int*)d_in[8];

  char* ws = (char*)d_ws;
  float*    t1       = (float*)(ws + 0);
  float*    t2       = (float*)(ws + 32768);
  float*    RR       = (float*)(ws + 65536);
  int*      C        = (int*)(ws + 81920);
  uint16_t* rank_pos = (uint16_t*)(ws + 100352);
  uint16_t* rank_neg = (uint16_t*)(ws + 165888);
  float*    buf_pos  = (float*)(ws + 690176);
  float*    buf_neg  = (float*)(ws + 821248);
  float*    out      = (float*)d_out;

  k_fused<<<5824, 256, 0, stream>>>(in_ent, out_ent, in_rel, out_rel, in_map, out_map,
                                    in_lab, pos_lab, neg_lab,
                                    t1, t2, RR, C, rank_pos, rank_neg,
                                    buf_pos, buf_neg, out);
  k_scan<<<1, 256, 0, stream>>>(C);
  k_final<<<1152, 256, 0, stream>>>(in_ent, out_ent, t1, t2, RR,
                                    in_lab, pos_lab, neg_lab,
                                    C, rank_pos, rank_neg, buf_pos, buf_neg, out);
}

// Round 12
// 44.499 us; speedup vs baseline: 1.2195x; 1.2195x over previous
//
#include <hip/hip_runtime.h>
#include <hip/hip_bf16.h>
#include <stdint.h>

#define ENT 250000
#define RELSZ 64
#define D 128
#define BATCH 32768
#define KNEG 8

// ---------------- workspace layout (byte offsets) ----------------
// t1       :       0 .. 32768    (64x128 f32)  out_rel - (n_inmap.out_rel) n_inmap
// t2       :   32768 .. 65536    (64x128 f32)  in_rel  - (n_outmap.in_rel) n_outmap
// RR       :   65536 .. 81920    (64x64  f32)  in_rel[i] . out_rel[p]
// C        :   81920 .. 100352   (4608 int)    block bucket counts -> exclusive scan
// rank_pos :  100352 .. 165888   (32768 u16)   block-local stable rank
// rank_neg :  165888 .. 690176   (262144 u16)
// LESSONS: R4: no __threadfence last-block pattern (~73us). R7: no single-block
// grid-serial scans. R8: no hipMemsetAsync on scratch. R10: no dependent staging
// prologue in the gather kernel. R11: no extra dot-buffer pass. R6 structure wins.

__device__ __forceinline__ float logsig(float x) {
  return fminf(x, 0.f) - log1pf(expf(-fabsf(x)));
}

// Fused: blocks [0,128) pos-count (+zero out), [128,1152) neg-count, [1152,1184) tables.
__global__ void k_prep(const float* __restrict__ in_rel, const float* __restrict__ out_rel,
                       const float* __restrict__ in_map, const float* __restrict__ out_map,
                       const int* __restrict__ in_lab, const int* __restrict__ pos_lab,
                       const int* __restrict__ neg_lab,
                       float* __restrict__ t1, float* __restrict__ t2, float* __restrict__ RR,
                       int* __restrict__ C, uint16_t* __restrict__ rank_pos,
                       uint16_t* __restrict__ rank_neg, float* __restrict__ out) {
  __shared__ float ls[4];
  __shared__ float sri[2][128];
  __shared__ int wc[4][4];
  int blk = blockIdx.x, t = threadIdx.x;

  if (blk >= 1152) {
    // ---- tables: 2 rel rows per block ----
    int sub = t >> 7, tt = t & 127;
    int p = (blk - 1152) * 2 + sub;
    float im = in_map[p * D + tt], om = out_map[p * D + tt];
    float ro = out_rel[p * D + tt], ri = in_rel[p * D + tt];
    float v, r, n_im, n_om;
    v = im * im;
#pragma unroll
    for (int off = 32; off > 0; off >>= 1) v += __shfl_xor(v, off, 64);
    if ((t & 63) == 0) ls[t >> 6] = v;
    __syncthreads();
    r = ls[sub * 2] + ls[sub * 2 + 1];
    n_im = im / fmaxf(sqrtf(r), 1e-12f);
    __syncthreads();
    v = om * om;
#pragma unroll
    for (int off = 32; off > 0; off >>= 1) v += __shfl_xor(v, off, 64);
    if ((t & 63) == 0) ls[t >> 6] = v;
    __syncthreads();
    r = ls[sub * 2] + ls[sub * 2 + 1];
    n_om = om / fmaxf(sqrtf(r), 1e-12f);
    __syncthreads();
    v = n_im * ro;
#pragma unroll
    for (int off = 32; off > 0; off >>= 1) v += __shfl_xor(v, off, 64);
    if ((t & 63) == 0) ls[t >> 6] = v;
    __syncthreads();
    float d1 = ls[sub * 2] + ls[sub * 2 + 1];
    __syncthreads();
    v = n_om * ri;
#pragma unroll
    for (int off = 32; off > 0; off >>= 1) v += __shfl_xor(v, off, 64);
    if ((t & 63) == 0) ls[t >> 6] = v;
    __syncthreads();
    float d2 = ls[sub * 2] + ls[sub * 2 + 1];
    t1[p * D + tt] = ro - d1 * n_im;
    t2[p * D + tt] = ri - d2 * n_om;
    sri[sub][tt] = ri;
    __syncthreads();
    int half = t >> 7, lq = t & 127;
    if (lq < RELSZ) {
      int pr = (blk - 1152) * 2 + half;
      const float* rq = out_rel + lq * D;
      const float* s = sri[half];
      float acc = 0.f;
#pragma unroll 8
      for (int d = 0; d < D; d += 4) {
        float4 r4 = *(const float4*)(rq + d);
        acc += s[d] * r4.x + s[d + 1] * r4.y + s[d + 2] * r4.z + s[d + 3] * r4.w;
      }
      RR[pr * RELSZ + lq] = acc;
    }
    return;
  }

  // ---- counting + stable block-local ranks ----
  int wave = t >> 6, lane = t & 63;
  int key, i;
  bool is_pos = blk < 128;
  if (is_pos) {
    i = blk * 256 + t;
    int il = in_lab[i], pl = pos_lab[i];
    key = ((il >= ENT) ? 2 : 0) | ((pl >= ENT) ? 1 : 0);
  } else {
    i = (blk - 128) * 256 + t;
    int il = in_lab[i >> 3], nl = neg_lab[i];
    key = ((il >= ENT) ? 2 : 0) | ((nl >= ENT) ? 1 : 0);
  }
  unsigned long long m[4];
#pragma unroll
  for (int v = 0; v < 4; v++) m[v] = __ballot(key == v);
  if (lane < 4) wc[wave][lane] = __popcll(m[lane]);
  int wrank = __popcll(m[key] & ((1ull << lane) - 1ull));
  __syncthreads();
  if (t < 4) {
    int s = wc[0][t] + wc[1][t] + wc[2][t] + wc[3][t];
    int idx = is_pos ? (t * 128 + blk) : (512 + t * 1024 + (blk - 128));
    C[idx] = s;
  }
  int wpre = 0;
  for (int w = 0; w < wave; w++) wpre += wc[w][key];
  uint16_t rk = (uint16_t)(wpre + wrank);
  if (is_pos) { rank_pos[i] = rk; out[i] = 0.f; }
  else        { rank_neg[i] = rk; }
}

// In-place exclusive scan of C[0..4607]. 1 block x 256 threads, 18 elems each.
__global__ void k_scan(int* __restrict__ C) {
  int t = threadIdx.x, lane = t & 63, w = t >> 6;
  int base = t * 18;
  int v[18];
  int s = 0;
#pragma unroll
  for (int j = 0; j < 18; j++) { v[j] = C[base + j]; s += v[j]; }
  int inc = s;
#pragma unroll
  for (int off = 1; off < 64; off <<= 1) {
    int x = __shfl_up(inc, off, 64);
    if (lane >= off) inc += x;
  }
  __shared__ int wsum[4];
  if (lane == 63) wsum[w] = inc;
  __syncthreads();
  int wpre = 0;
  for (int i = 0; i < w; i++) wpre += wsum[i];
  int run = wpre + inc - s;  // exclusive prefix of this thread's chunk
#pragma unroll
  for (int j = 0; j < 18; j++) { C[base + j] = run; run += v[j]; }
}

// Main: 4 lanes per pair, 32 pairs per wave (2 per group, both issued before any
// consumption -> 32 row-gathers in flight per lane-set; tests the MLP hypothesis).
// Blocks [0,256): pos pairs. Blocks [256,2304): neg pairs (4 rows x 8 negs per wave).
__global__ void __launch_bounds__(256, 3)
k_main(const float* __restrict__ in_ent, const float* __restrict__ out_ent,
       const float* __restrict__ t1, const float* __restrict__ t2,
       const float* __restrict__ RR,
       const int* __restrict__ in_lab, const int* __restrict__ pos_lab,
       const int* __restrict__ neg_lab,
       const int* __restrict__ C, const uint16_t* __restrict__ rank_pos,
       const uint16_t* __restrict__ rank_neg, float* __restrict__ out) {
  int blk = blockIdx.x, t = threadIdx.x;
  int wave = t >> 6, lane = t & 63;
  int q = lane & 3, g = lane >> 2;  // 16 groups of 4 lanes

  bool is_pos = blk < 256;
  int w = (is_pos ? blk : blk - 256) * 4 + wave;
  int i0 = w * 32 + g;       // pair chunk A
  int i1 = i0 + 16;          // pair chunk B

  int il0, o0, il1, o1;
  if (is_pos) { il0 = in_lab[i0]; o0 = pos_lab[i0]; il1 = in_lab[i1]; o1 = pos_lab[i1]; }
  else        { il0 = in_lab[i0 >> 3]; o0 = neg_lab[i0];
                il1 = in_lab[i1 >> 3]; o1 = neg_lab[i1]; }
  bool ei0 = il0 < ENT, eo0 = o0 < ENT, ei1 = il1 < ENT, eo1 = o1 < ENT;
  int iid0 = ei0 ? il0 : il0 - ENT, oid0 = eo0 ? o0 : o0 - ENT;
  int iid1 = ei1 ? il1 : il1 - ENT, oid1 = eo1 ? o1 : o1 - ENT;
  int key0 = (ei0 ? 0 : 2) | (eo0 ? 0 : 1);
  int key1 = (ei1 ? 0 : 2) | (eo1 ? 0 : 1);

  // small dest loads (independent; consumed only at the very end)
  int rk0 = is_pos ? (int)rank_pos[i0] : (int)rank_neg[i0];
  int rk1 = is_pos ? (int)rank_pos[i1] : (int)rank_neg[i1];
  int cidx0 = is_pos ? (key0 * 128 + (i0 >> 8)) : (512 + key0 * 1024 + (i0 >> 8));
  int cidx1 = is_pos ? (key1 * 128 + (i1 >> 8)) : (512 + key1 * 1024 + (i1 >> 8));
  int cb0 = C[cidx0], cb1 = C[cidx1];

  // issue all 32 row loads before any consumption
  const float* Lp0 = (ei0 ? in_ent + (size_t)iid0 * D : t2 + (size_t)iid0 * D) + q * 4;
  const float* Rp0 = (eo0 ? out_ent + (size_t)oid0 * D : t1 + (size_t)oid0 * D) + q * 4;
  const float* Lp1 = (ei1 ? in_ent + (size_t)iid1 * D : t2 + (size_t)iid1 * D) + q * 4;
  const float* Rp1 = (eo1 ? out_ent + (size_t)oid1 * D : t1 + (size_t)oid1 * D) + q * 4;
  float4 L0[8], R0[8], L1[8], R1[8];
#pragma unroll
  for (int k = 0; k < 8; k++) L0[k] = *(const float4*)(Lp0 + k * 16);
#pragma unroll
  for (int k = 0; k < 8; k++) R0[k] = *(const float4*)(Rp0 + k * 16);
#pragma unroll
  for (int k = 0; k < 8; k++) L1[k] = *(const float4*)(Lp1 + k * 16);
#pragma unroll
  for (int k = 0; k < 8; k++) R1[k] = *(const float4*)(Rp1 + k * 16);

  float p0 = 0.f, p1 = 0.f;
#pragma unroll
  for (int k = 0; k < 8; k++)
    p0 += L0[k].x * R0[k].x + L0[k].y * R0[k].y + L0[k].z * R0[k].z + L0[k].w * R0[k].w;
#pragma unroll
  for (int k = 0; k < 8; k++)
    p1 += L1[k].x * R1[k].x + L1[k].y * R1[k].y + L1[k].z * R1[k].z + L1[k].w * R1[k].w;
  p0 += __shfl_xor(p0, 1, 64);
  p0 += __shfl_xor(p0, 2, 64);
  p1 += __shfl_xor(p1, 1, 64);
  p1 += __shfl_xor(p1, 2, 64);

  if (key0 == 3) p0 = RR[iid0 * RELSZ + oid0];  // rel-rel: exact table value
  if (key1 == 3) p1 = RR[iid1 * RELSZ + oid1];

  if (is_pos) {
    if (q == 0) {
      atomicAdd(out + cb0 + rk0, -logsig(p0));
      atomicAdd(out + cb1 + rk1, -logsig(p1));
    }
    return;
  }

  // neg: per chunk, dest uniform per group; tree-combine the 8 groups of each half
#pragma unroll
  for (int c = 0; c < 2; c++) {
    int dest = ((c == 0 ? cb0 + rk0 : cb1 + rk1) - BATCH) >> 3;
    float dot = (c == 0) ? p0 : p1;
    float myval = (q == 0) ? -logsig(-dot) : 0.f;
    float v = myval;
    int d = dest, eq = 1;
#pragma unroll
    for (int off = 4; off <= 16; off <<= 1) {
      float vv = __shfl_xor(v, off, 64);
      int dd = __shfl_xor(d, off, 64);
      int ee = __shfl_xor(eq, off, 64);
      eq = eq & ee & (dd == d ? 1 : 0);
      v += vv;
    }
    if (eq) {
      if (lane == 0 || lane == 32) atomicAdd(out + d, v);
    } else if (q == 0) {
      atomicAdd(out + dest, myval);
    }
  }
}

extern "C" void kernel_launch(void* const* d_in, const int* in_sizes, int n_in,
                              void* d_out, int out_size, void* d_ws, size_t ws_size,
                              hipStream_t stream) {
  const float* in_ent  = (const float*)d_in[0];
  const float* out_ent = (const float*)d_in[1];
  const float* in_rel  = (const float*)d_in[2];
  const float* out_rel = (const float*)d_in[3];
  const float* in_map  = (const float*)d_in[4];
  const float* out_map = (const float*)d_in[5];
  const int* in_lab  = (const int*)d_in[6];
  const int* pos_lab = (const int*)d_in[7];
  const int* neg_lab = (const int*)d_in[8];

  char* ws = (char*)d_ws;
  float*    t1       = (float*)(ws + 0);
  float*    t2       = (float*)(ws + 32768);
  float*    RR       = (float*)(ws + 65536);
  int*      C        = (int*)(ws + 81920);
  uint16_t* rank_pos = (uint16_t*)(ws + 100352);
  uint16_t* rank_neg = (uint16_t*)(ws + 165888);
  float*    out      = (float*)d_out;

  k_prep<<<1184, 256, 0, stream>>>(in_rel, out_rel, in_map, out_map,
                                   in_lab, pos_lab, neg_lab,
                                   t1, t2, RR, C, rank_pos, rank_neg, out);
  k_scan<<<1, 256, 0, stream>>>(C);
  k_main<<<2304, 256, 0, stream>>>(in_ent, out_ent, t1, t2, RR,
                                   in_lab, pos_lab, neg_lab,
                                   C, rank_pos, rank_neg, out);
}

// Round 13
// 44.354 us; speedup vs baseline: 1.2235x; 1.0033x over previous
//
#include <hip/hip_runtime.h>
#include <hip/hip_bf16.h>
#include <stdint.h>

#define ENT 250000
#define RELSZ 64
#define D 128
#define BATCH 32768
#define KNEG 8

// ---------------- workspace layout (byte offsets) ----------------
// t1       :       0 .. 32768    (64x128 f32)  out_rel - (n_inmap.out_rel) n_inmap
// t2       :   32768 .. 65536    (64x128 f32)  in_rel  - (n_outmap.in_rel) n_outmap
// RR       :   65536 .. 81920    (64x64  f32)  in_rel[i] . out_rel[p]
// C        :   81920 .. 100352   (4608 int)    block bucket counts -> exclusive scan
// rank_pos :  100352 .. 165888   (32768 u16)   block-local stable rank
// rank_neg :  165888 .. 690176   (262144 u16)
// LEDGER (12 rounds): R6 structure is optimal-known (43.6us). Failed alternatives:
// R4 __threadfence last-block (-78us), R7 single-block serial scan (-83us),
// R8 hipMemsetAsync on scratch (-11us), R10 LDS staging prologue in gather (-7us),
// R11 split dot-buffer pass (-11us), R12 2x MLP @ 3 waves/SIMD (=, not better).
// k_main is MSHR/latency-bound on compulsory random 512B-row gathers (~83MB @
// ~3TB/s; MSHR model 64 lines x 375ns x 256CU = 2.8TB/s matches).

__device__ __forceinline__ float logsig(float x) {
  return fminf(x, 0.f) - log1pf(expf(-fabsf(x)));
}

// Fused: blocks [0,128) pos-count (+zero out), [128,1152) neg-count, [1152,1184) tables.
__global__ void k_prep(const float* __restrict__ in_rel, const float* __restrict__ out_rel,
                       const float* __restrict__ in_map, const float* __restrict__ out_map,
                       const int* __restrict__ in_lab, const int* __restrict__ pos_lab,
                       const int* __restrict__ neg_lab,
                       float* __restrict__ t1, float* __restrict__ t2, float* __restrict__ RR,
                       int* __restrict__ C, uint16_t* __restrict__ rank_pos,
                       uint16_t* __restrict__ rank_neg, float* __restrict__ out) {
  __shared__ float ls[4];
  __shared__ float sri[2][128];
  __shared__ int wc[4][4];
  int blk = blockIdx.x, t = threadIdx.x;

  if (blk >= 1152) {
    // ---- tables: 2 rel rows per block ----
    int sub = t >> 7, tt = t & 127;
    int p = (blk - 1152) * 2 + sub;
    float im = in_map[p * D + tt], om = out_map[p * D + tt];
    float ro = out_rel[p * D + tt], ri = in_rel[p * D + tt];
    float v, r, n_im, n_om;
    v = im * im;
#pragma unroll
    for (int off = 32; off > 0; off >>= 1) v += __shfl_xor(v, off, 64);
    if ((t & 63) == 0) ls[t >> 6] = v;
    __syncthreads();
    r = ls[sub * 2] + ls[sub * 2 + 1];
    n_im = im / fmaxf(sqrtf(r), 1e-12f);
    __syncthreads();
    v = om * om;
#pragma unroll
    for (int off = 32; off > 0; off >>= 1) v += __shfl_xor(v, off, 64);
    if ((t & 63) == 0) ls[t >> 6] = v;
    __syncthreads();
    r = ls[sub * 2] + ls[sub * 2 + 1];
    n_om = om / fmaxf(sqrtf(r), 1e-12f);
    __syncthreads();
    v = n_im * ro;
#pragma unroll
    for (int off = 32; off > 0; off >>= 1) v += __shfl_xor(v, off, 64);
    if ((t & 63) == 0) ls[t >> 6] = v;
    __syncthreads();
    float d1 = ls[sub * 2] + ls[sub * 2 + 1];
    __syncthreads();
    v = n_om * ri;
#pragma unroll
    for (int off = 32; off > 0; off >>= 1) v += __shfl_xor(v, off, 64);
    if ((t & 63) == 0) ls[t >> 6] = v;
    __syncthreads();
    float d2 = ls[sub * 2] + ls[sub * 2 + 1];
    t1[p * D + tt] = ro - d1 * n_im;
    t2[p * D + tt] = ri - d2 * n_om;
    sri[sub][tt] = ri;
    __syncthreads();
    int half = t >> 7, lq = t & 127;
    if (lq < RELSZ) {
      int pr = (blk - 1152) * 2 + half;
      const float* rq = out_rel + lq * D;
      const float* s = sri[half];
      float acc = 0.f;
#pragma unroll 8
      for (int d = 0; d < D; d += 4) {
        float4 r4 = *(const float4*)(rq + d);
        acc += s[d] * r4.x + s[d + 1] * r4.y + s[d + 2] * r4.z + s[d + 3] * r4.w;
      }
      RR[pr * RELSZ + lq] = acc;
    }
    return;
  }

  // ---- counting + stable block-local ranks ----
  int wave = t >> 6, lane = t & 63;
  int key, i;
  bool is_pos = blk < 128;
  if (is_pos) {
    i = blk * 256 + t;
    int il = in_lab[i], pl = pos_lab[i];
    key = ((il >= ENT) ? 2 : 0) | ((pl >= ENT) ? 1 : 0);
  } else {
    i = (blk - 128) * 256 + t;
    int il = in_lab[i >> 3], nl = neg_lab[i];
    key = ((il >= ENT) ? 2 : 0) | ((nl >= ENT) ? 1 : 0);
  }
  unsigned long long m[4];
#pragma unroll
  for (int v = 0; v < 4; v++) m[v] = __ballot(key == v);
  if (lane < 4) wc[wave][lane] = __popcll(m[lane]);
  int wrank = __popcll(m[key] & ((1ull << lane) - 1ull));
  __syncthreads();
  if (t < 4) {
    int s = wc[0][t] + wc[1][t] + wc[2][t] + wc[3][t];
    int idx = is_pos ? (t * 128 + blk) : (512 + t * 1024 + (blk - 128));
    C[idx] = s;
  }
  int wpre = 0;
  for (int w = 0; w < wave; w++) wpre += wc[w][key];
  uint16_t rk = (uint16_t)(wpre + wrank);
  if (is_pos) { rank_pos[i] = rk; out[i] = 0.f; }
  else        { rank_neg[i] = rk; }
}

// In-place exclusive scan of C[0..4607]. 1 block x 256 threads, 18 elems each.
__global__ void k_scan(int* __restrict__ C) {
  int t = threadIdx.x, lane = t & 63, w = t >> 6;
  int base = t * 18;
  int v[18];
  int s = 0;
#pragma unroll
  for (int j = 0; j < 18; j++) { v[j] = C[base + j]; s += v[j]; }
  int inc = s;
#pragma unroll
  for (int off = 1; off < 64; off <<= 1) {
    int x = __shfl_up(inc, off, 64);
    if (lane >= off) inc += x;
  }
  __shared__ int wsum[4];
  if (lane == 63) wsum[w] = inc;
  __syncthreads();
  int wpre = 0;
  for (int i = 0; i < w; i++) wpre += wsum[i];
  int run = wpre + inc - s;  // exclusive prefix of this thread's chunk
#pragma unroll
  for (int j = 0; j < 18; j++) { C[base + j] = run; run += v[j]; }
}

// Main: 4 lanes per pair, 16 pairs per wave.
// Blocks [0,512): pos pairs. Blocks [512,4608): neg pairs (2 rows x 8 negs per wave).
// Neg waves combine the up-to-8 same-dest values per row into one atomic (shfl tree
// with dest-equality check; fallback to per-pair atomics on mixed dests).
__global__ void __launch_bounds__(256, 4)
k_main(const float* __restrict__ in_ent, const float* __restrict__ out_ent,
       const float* __restrict__ t1, const float* __restrict__ t2,
       const float* __restrict__ RR,
       const int* __restrict__ in_lab, const int* __restrict__ pos_lab,
       const int* __restrict__ neg_lab,
       const int* __restrict__ C, const uint16_t* __restrict__ rank_pos,
       const uint16_t* __restrict__ rank_neg, float* __restrict__ out) {
  int blk = blockIdx.x, t = threadIdx.x;
  int wave = t >> 6, lane = t & 63;
  int q = lane & 3, g = lane >> 2;  // 16 groups of 4 lanes

  bool is_pos = blk < 512;
  int w = (is_pos ? blk : blk - 512) * 4 + wave;
  int i = w * 16 + g;  // pair index within its class

  int il, o;
  if (is_pos) { il = in_lab[i]; o = pos_lab[i]; }
  else        { il = in_lab[i >> 3]; o = neg_lab[i]; }
  bool ei = il < ENT;
  int iid = ei ? il : il - ENT;
  bool eo = o < ENT;
  int oid = eo ? o : o - ENT;
  int key = (ei ? 0 : 2) | (eo ? 0 : 1);

  // small loads issued early (all lanes of a group load same addr -> dedup)
  int rk = is_pos ? (int)rank_pos[i] : (int)rank_neg[i];
  int cidx = is_pos ? (key * 128 + (i >> 8)) : (512 + key * 1024 + (i >> 8));
  int cbase = C[cidx];

  const float* Lp = (ei ? in_ent + (size_t)iid * D : t2 + (size_t)iid * D) + q * 4;
  const float* Rp = (eo ? out_ent + (size_t)oid * D : t1 + (size_t)oid * D) + q * 4;
  float4 L[8], R[8];
#pragma unroll
  for (int k = 0; k < 8; k++) L[k] = *(const float4*)(Lp + k * 16);
#pragma unroll
  for (int k = 0; k < 8; k++) R[k] = *(const float4*)(Rp + k * 16);

  float p = 0.f;
#pragma unroll
  for (int k = 0; k < 8; k++)
    p += L[k].x * R[k].x + L[k].y * R[k].y + L[k].z * R[k].z + L[k].w * R[k].w;
  p += __shfl_xor(p, 1, 64);
  p += __shfl_xor(p, 2, 64);

  float dot = p;
  if (!ei && !eo) dot = RR[iid * RELSZ + oid];  // rel-rel pair: exact table value

  if (is_pos) {
    if (q == 0) atomicAdd(out + cbase + rk, -logsig(dot));
    return;
  }

  // neg: dest uniform per group; tree-combine across the 8 groups of each 32-lane half
  int dest = (cbase + rk - BATCH) >> 3;
  float myval = (q == 0) ? -logsig(-dot) : 0.f;
  float v = myval;
  int d = dest;
  int eq = 1;
#pragma unroll
  for (int off = 4; off <= 16; off <<= 1) {
    float vv = __shfl_xor(v, off, 64);
    int dd = __shfl_xor(d, off, 64);
    int ee = __shfl_xor(eq, off, 64);
    eq = eq & ee & (dd == d ? 1 : 0);
    v += vv;
  }
  if (eq) {
    if (lane == 0 || lane == 32) atomicAdd(out + d, v);
  } else if (q == 0) {
    atomicAdd(out + dest, myval);
  }
}

extern "C" void kernel_launch(void* const* d_in, const int* in_sizes, int n_in,
                              void* d_out, int out_size, void* d_ws, size_t ws_size,
                              hipStream_t stream) {
  const float* in_ent  = (const float*)d_in[0];
  const float* out_ent = (const float*)d_in[1];
  const float* in_rel  = (const float*)d_in[2];
  const float* out_rel = (const float*)d_in[3];
  const float* in_map  = (const float*)d_in[4];
  const float* out_map = (const float*)d_in[5];
  const int* in_lab  = (const int*)d_in[6];
  const int* pos_lab = (const int*)d_in[7];
  const int* neg_lab = (const int*)d_in[8];

  char* ws = (char*)d_ws;
  float*    t1       = (float*)(ws + 0);
  float*    t2       = (float*)(ws + 32768);
  float*    RR       = (float*)(ws + 65536);
  int*      C        = (int*)(ws + 81920);
  uint16_t* rank_pos = (uint16_t*)(ws + 100352);
  uint16_t* rank_neg = (uint16_t*)(ws + 165888);
  float*    out      = (float*)d_out;

  k_prep<<<1184, 256, 0, stream>>>(in_rel, out_rel, in_map, out_map,
                                   in_lab, pos_lab, neg_lab,
                                   t1, t2, RR, C, rank_pos, rank_neg, out);
  k_scan<<<1, 256, 0, stream>>>(C);
  k_main<<<4608, 256, 0, stream>>>(in_ent, out_ent, t1, t2, RR,
                                   in_lab, pos_lab, neg_lab,
                                   C, rank_pos, rank_neg, out);
}